// Round 4
// baseline (644.770 us; speedup 1.0000x reference)
//
#include <hip/hip_runtime.h>

typedef __bf16 bf16x8 __attribute__((ext_vector_type(8)));
typedef __bf16 bf16x4 __attribute__((ext_vector_type(4)));
typedef float f32x4 __attribute__((ext_vector_type(4)));

__device__ __forceinline__ f32x4 mfma16(bf16x8 a, bf16x8 b, f32x4 c) {
  return __builtin_amdgcn_mfma_f32_16x16x32_bf16(a, b, c, 0, 0, 0);
}

__device__ __forceinline__ void load_lds16(const void* g, void* l) {
  __builtin_amdgcn_global_load_lds(
      (const __attribute__((address_space(1))) void*)g,
      (__attribute__((address_space(3))) void*)l, 16, 0, 0);
}

// Bijective XCD chunk swizzle (m204).
template <int NWG>
__device__ __forceinline__ int xcd_swz(int orig) {
  constexpr int NX = 8;
  constexpr int q = NWG / NX;
  constexpr int r = NWG % NX;
  const int xcd = orig % NX;
  const int pos = orig / NX;
  if constexpr (r == 0) {
    return xcd * q + pos;
  } else {
    return (xcd < r ? xcd * (q + 1) : r * (q + 1) + (xcd - r) * q) + pos;
  }
}

// ---------------- weight transpose + cast: W[k][n] (fp32) -> WT[n][k] (bf16) ----------------
__global__ __launch_bounds__(256) void prep_w_kernel(
    const float* __restrict__ Wq, const float* __restrict__ Wk,
    const float* __restrict__ Wv, const float* __restrict__ Wo,
    __bf16* __restrict__ WqT, __bf16* __restrict__ WkvT, __bf16* __restrict__ WoT) {
  __shared__ float tile[32][33];
  const int z = blockIdx.z;
  const float* W = (z == 0) ? Wq : (z == 1) ? Wk : (z == 2) ? Wv : Wo;
  __bf16* out = (z == 0) ? WqT : (z == 3) ? WoT : WkvT;
  const int rowOff = (z == 2) ? 768 : 0;
  const int tx = threadIdx.x, ty = threadIdx.y;
  const int x = blockIdx.x * 32 + tx;  // n (fast dim of W)
  const int y = blockIdx.y * 32 + ty;  // k
#pragma unroll
  for (int i = 0; i < 32; i += 8) tile[ty + i][tx] = W[(size_t)(y + i) * 768 + x];
  __syncthreads();
  const int nx = blockIdx.y * 32 + tx;  // k (fast dim of WT)
  const int ny = blockIdx.x * 32 + ty;  // n
#pragma unroll
  for (int i = 0; i < 32; i += 8)
    out[(size_t)(rowOff + ny + i) * 768 + nx] = (__bf16)tile[tx][ty + i];
}

// ---------------- LayerNorm + cast: e (fp32) -> en (bf16 normalized) ----------------
__global__ __launch_bounds__(256) void ln_kernel(
    const float* __restrict__ e, const float* __restrict__ gam,
    const float* __restrict__ bet, __bf16* __restrict__ en) {
  const int lane = threadIdx.x & 63;
  const int wid = threadIdx.x >> 6;
  const size_t row = (size_t)blockIdx.x * 4 + wid;
  const float* p = e + row * 768;
  float x[12];
  float sum = 0.f;
#pragma unroll
  for (int s = 0; s < 3; ++s) {
    f32x4 v = *(const f32x4*)(p + (s * 64 + lane) * 4);
#pragma unroll
    for (int q = 0; q < 4; ++q) { x[s * 4 + q] = v[q]; sum += v[q]; }
  }
#pragma unroll
  for (int d = 1; d < 64; d <<= 1) sum += __shfl_xor(sum, d);
  const float m = sum * (1.f / 768.f);
  float vs = 0.f;
#pragma unroll
  for (int q = 0; q < 12; ++q) { float d = x[q] - m; vs += d * d; }
#pragma unroll
  for (int d = 1; d < 64; d <<= 1) vs += __shfl_xor(vs, d);
  const float rr = rsqrtf(vs * (1.f / 768.f) + 1e-5f);
  __bf16* o = en + row * 768;
#pragma unroll
  for (int s = 0; s < 3; ++s) {
    f32x4 g4 = *(const f32x4*)(gam + (s * 64 + lane) * 4);
    f32x4 b4 = *(const f32x4*)(bet + (s * 64 + lane) * 4);
    bf16x4 pk;
#pragma unroll
    for (int q = 0; q < 4; ++q) pk[q] = (__bf16)((x[s * 4 + q] - m) * rr * g4[q] + b4[q]);
    *(bf16x4*)(o + (s * 64 + lane) * 4) = pk;
  }
}

// ---------------- fp32 -> bf16 cast (h) ----------------
__global__ __launch_bounds__(256) void cast_kernel(
    const float* __restrict__ in, __bf16* __restrict__ out, int n4) {
  int i = blockIdx.x * 256 + threadIdx.x;
  const int stride = gridDim.x * 256;
  for (; i < n4; i += stride) {
    f32x4 v = ((const f32x4*)in)[i];
    bf16x4 o;
#pragma unroll
    for (int q = 0; q < 4; ++q) o[q] = (__bf16)v[q];
    ((bf16x4*)out)[i] = o;
  }
}

// ---------------- templated 128x128 MFMA GEMM, dbuf global_load_lds pipeline ----------------
// A [M x 768] bf16 @ WT[n][k] bf16.  4 waves (2x2), each 64x64.
// T3-minimal 2-phase: STAGE(next) issued BEFORE compute(cur); one
// vmcnt(0)+barrier per K-step (__syncthreads emits the drain).
enum { MODE_Q = 0, MODE_KV = 1, MODE_O = 2 };

template <int MODE, int NC, int NWG>
__global__ __launch_bounds__(256) void gemm_kernel(
    const __bf16* __restrict__ A,    // en (Q) / h_bf16 (KV) / o block-layout (O)
    const __bf16* __restrict__ WT,   // [N][768] bf16
    const float* __restrict__ bias0, const float* __restrict__ bias1,
    const float* __restrict__ eres,  // O only: fp32 residual e
    __bf16* __restrict__ dst0, __bf16* __restrict__ dst1,
    float* __restrict__ outp) {
  __shared__ __bf16 As[2][8192];
  __shared__ __bf16 Bs[2][8192];
  const int wgid = xcd_swz<NWG>(blockIdx.x);
  const int rowBase = (wgid / NC) * 128;
  const int colBase = (wgid % NC) * 128;
  const int t = threadIdx.x;
  const int lane = t & 63, wid = t >> 6;
  const int wm = wid >> 1, wn = wid & 1;
  const int lr = lane & 15, lg = lane >> 4;
  const int srow = lane >> 3;          // staging: row within 8-row chunk
  const int skcol = (lane & 7) * 8;    // staging: k-offset within 64-col tile
  f32x4 acc[4][4] = {};

  auto stage = [&](int kbb, int buf) {
#pragma unroll
    for (int s = 0; s < 4; ++s) {
      const int chunk = s * 4 + wid;          // 0..15, 8 rows each
      const int rowIn = chunk * 8 + srow;
      const __bf16* ga;
      if constexpr (MODE == MODE_O) {
        const int r = rowBase + rowIn;
        ga = A + ((((size_t)(r >> 6)) * 12 + kbb) << 12) + ((r & 63) << 6) + skcol;
      } else {
        ga = A + (size_t)(rowBase + rowIn) * 768 + kbb * 64 + skcol;
      }
      load_lds16(ga, &As[buf][chunk * 512]);
      const __bf16* gb = WT + (size_t)(colBase + rowIn) * 768 + kbb * 64 + skcol;
      load_lds16(gb, &Bs[buf][chunk * 512]);
    }
  };
  auto compute = [&](int buf) {
#pragma unroll
    for (int kc = 0; kc < 2; ++kc) {
      bf16x8 a[4], b[4];
#pragma unroll
      for (int it = 0; it < 4; ++it)
        a[it] = *(const bf16x8*)&As[buf][(wm * 64 + it * 16 + lr) * 64 + kc * 32 + lg * 8];
#pragma unroll
      for (int jt = 0; jt < 4; ++jt)
        b[jt] = *(const bf16x8*)&Bs[buf][(wn * 64 + jt * 16 + lr) * 64 + kc * 32 + lg * 8];
#pragma unroll
      for (int it = 0; it < 4; ++it)
#pragma unroll
        for (int jt = 0; jt < 4; ++jt)
          acc[it][jt] = mfma16(a[it], b[jt], acc[it][jt]);
    }
  };

  // prologue: stage tile 0, drain, then pipelined loop (tile kb in buf[kb&1])
  stage(0, 0);
  __syncthreads();
#pragma unroll
  for (int kb = 0; kb < 11; ++kb) {
    const int cur = kb & 1;
    stage(kb + 1, cur ^ 1);   // loads for next tile in flight during MFMA
    compute(cur);
    __syncthreads();          // vmcnt(0)+lgkmcnt(0)+barrier: next tile ready
  }
  compute(1);

  // ---- epilogue ----
  const int roww = rowBase + wm * 64;
  const int colw = colBase + wn * 64;
#pragma unroll
  for (int it = 0; it < 4; ++it) {
#pragma unroll
    for (int jt = 0; jt < 4; ++jt) {
      const int c = colw + jt * 16 + lr;
#pragma unroll
      for (int rg = 0; rg < 4; ++rg) {
        const int r = roww + it * 16 + lg * 4 + rg;
        const float val = acc[it][jt][rg];
        if constexpr (MODE == MODE_O) {
          outp[(size_t)r * 768 + c] = val + bias0[c] + eres[(size_t)r * 768 + c];
        } else if constexpr (MODE == MODE_Q) {
          dst0[((((size_t)(r >> 6)) * 12 + (c >> 6)) << 12) + ((r & 63) << 6) + (c & 63)] =
              (__bf16)(val + bias0[c]);
        } else {  // KV: c<768 -> k[bc][h][j][d]; else v transposed [bc][h][d][j]
          if (c < 768) {
            dst0[((((size_t)(r >> 6)) * 12 + (c >> 6)) << 12) + ((r & 63) << 6) + (c & 63)] =
                (__bf16)(val + bias0[c]);
          } else {
            const int c2 = c - 768;
            dst1[((((size_t)(r >> 6)) * 12 + (c2 >> 6)) << 12) + ((c2 & 63) << 6) + (r & 63)] =
                (__bf16)(val + bias1[c2]);
          }
        }
      }
    }
  }
}

// ---------------- attention: one wave per (b,c,n,h); i=j=d=64 ----------------
__global__ __launch_bounds__(64) void attn_kernel(
    const __bf16* __restrict__ q, const __bf16* __restrict__ k,
    const __bf16* __restrict__ v, __bf16* __restrict__ o) {
  const int gid = xcd_swz<12288>(blockIdx.x);
  const int n = gid & 3;
  const int bh = gid >> 2;
  const int h = bh % 12;
  const int bc = bh / 12;
  const __bf16* qp = q + (((size_t)(bc * 4 + n) * 12 + h) << 12);
  const __bf16* kp = k + (((size_t)bc * 12 + h) << 12);
  const __bf16* vp = v + (((size_t)bc * 12 + h) << 12);
  __bf16* op = o + (((size_t)(bc * 4 + n) * 12 + h) << 12);
  const int lane = threadIdx.x;
  const int lr = lane & 15, lg = lane >> 4;
  __shared__ __bf16 P[64][72];

  bf16x8 qf[4][2], kf[4][2];
#pragma unroll
  for (int it = 0; it < 4; ++it)
#pragma unroll
    for (int kc = 0; kc < 2; ++kc)
      qf[it][kc] = *(const bf16x8*)(qp + (it * 16 + lr) * 64 + kc * 32 + lg * 8);
#pragma unroll
  for (int jt = 0; jt < 4; ++jt)
#pragma unroll
    for (int kc = 0; kc < 2; ++kc)
      kf[jt][kc] = *(const bf16x8*)(kp + (jt * 16 + lr) * 64 + kc * 32 + lg * 8);

  // S^T = k @ q^T : lane holds S[i = it*16+lr][j = jt*16+lg*4+rg]
  f32x4 s[4][4] = {};
#pragma unroll
  for (int kc = 0; kc < 2; ++kc)
#pragma unroll
    for (int jt = 0; jt < 4; ++jt)
#pragma unroll
      for (int it = 0; it < 4; ++it)
        s[jt][it] = mfma16(kf[jt][kc], qf[it][kc], s[jt][it]);

  float recip[4];
#pragma unroll
  for (int it = 0; it < 4; ++it) {
    float m = -1e30f;
#pragma unroll
    for (int jt = 0; jt < 4; ++jt)
#pragma unroll
      for (int rg = 0; rg < 4; ++rg) m = fmaxf(m, s[jt][it][rg]);
    m = fmaxf(m, __shfl_xor(m, 16));
    m = fmaxf(m, __shfl_xor(m, 32));
    float sum = 0.f;
#pragma unroll
    for (int jt = 0; jt < 4; ++jt) {
      bf16x4 pk;
#pragma unroll
      for (int rg = 0; rg < 4; ++rg) {
        float p = __expf((s[jt][it][rg] - m) * 0.125f);
        sum += p;
        pk[rg] = (__bf16)p;
      }
      *(bf16x4*)&P[it * 16 + lr][jt * 16 + lg * 4] = pk;
    }
    sum += __shfl_xor(sum, 16);
    sum += __shfl_xor(sum, 32);
    recip[it] = 1.f / sum;
  }
  __syncthreads();

  bf16x8 vf[4][2];
#pragma unroll
  for (int dt = 0; dt < 4; ++dt)
#pragma unroll
    for (int kc = 0; kc < 2; ++kc)
      vf[dt][kc] = *(const bf16x8*)(vp + (dt * 16 + lr) * 64 + kc * 32 + lg * 8);
  f32x4 oacc[4][4] = {};
#pragma unroll
  for (int kc = 0; kc < 2; ++kc) {
    bf16x8 pf[4];
#pragma unroll
    for (int it = 0; it < 4; ++it)
      pf[it] = *(const bf16x8*)&P[it * 16 + lr][kc * 32 + lg * 8];
#pragma unroll
    for (int dt = 0; dt < 4; ++dt)
#pragma unroll
      for (int it = 0; it < 4; ++it)
        oacc[dt][it] = mfma16(vf[dt][kc], pf[it], oacc[dt][it]);
  }
#pragma unroll
  for (int it = 0; it < 4; ++it) {
    const float rc = recip[it];
#pragma unroll
    for (int dt = 0; dt < 4; ++dt) {
      bf16x4 pk;
#pragma unroll
      for (int rg = 0; rg < 4; ++rg) pk[rg] = (__bf16)(oacc[dt][it][rg] * rc);
      *(bf16x4*)(op + (size_t)(it * 16 + lr) * 64 + dt * 16 + lg * 4) = pk;
    }
  }
}

extern "C" void kernel_launch(void* const* d_in, const int* in_sizes, int n_in,
                              void* d_out, int out_size, void* d_ws, size_t ws_size,
                              hipStream_t stream) {
  const float* e  = (const float*)d_in[0];
  const float* h  = (const float*)d_in[1];
  const float* Wq = (const float*)d_in[2];
  const float* bq = (const float*)d_in[3];
  const float* Wk = (const float*)d_in[4];
  const float* bk = (const float*)d_in[5];
  const float* Wv = (const float*)d_in[6];
  const float* bv = (const float*)d_in[7];
  const float* Wo = (const float*)d_in[8];
  const float* bo = (const float*)d_in[9];
  const float* g  = (const float*)d_in[10];
  const float* b  = (const float*)d_in[11];
  float* outp = (float*)d_out;
  char* ws = (char*)d_ws;

  // workspace layout (aliasing: en dead after Q-GEMM, region reused by h/k/v)
  __bf16* WqT  = (__bf16*)(ws);                    // 1,179,648
  __bf16* WkvT = (__bf16*)(ws + 1179648);          // 2,359,296
  __bf16* WoT  = (__bf16*)(ws + 3538944);          // 1,179,648
  char* R1 = ws + 4718592;                         // 100,663,296 shared region
  __bf16* en    = (__bf16*)(R1);                   // 65536*768*2 (live: ln -> Q-GEMM)
  __bf16* h_bf  = (__bf16*)(R1);                   // 16384*768*2 (live after Q-GEMM)
  __bf16* k_ws  = (__bf16*)(R1 + 25165824);
  __bf16* v_ws  = (__bf16*)(R1 + 50331648);
  __bf16* q_ws  = (__bf16*)(ws + 105381888);       // 100,663,296 (o written in-place)

  prep_w_kernel<<<dim3(24, 24, 4), dim3(32, 8), 0, stream>>>(Wq, Wk, Wv, Wo, WqT, WkvT, WoT);
  ln_kernel<<<16384, 256, 0, stream>>>(e, g, b, en);
  gemm_kernel<MODE_Q, 6, 3072><<<3072, 256, 0, stream>>>(
      en, WqT, bq, nullptr, nullptr, q_ws, nullptr, nullptr);
  cast_kernel<<<2048, 256, 0, stream>>>(h, h_bf, 16384 * 768 / 4);
  gemm_kernel<MODE_KV, 12, 1536><<<1536, 256, 0, stream>>>(
      h_bf, WkvT, bk, bv, nullptr, k_ws, v_ws, nullptr);
  attn_kernel<<<12288, 64, 0, stream>>>(q_ws, k_ws, v_ws, q_ws);
  gemm_kernel<MODE_O, 6, 3072><<<3072, 256, 0, stream>>>(
      q_ws, WoT, bo, nullptr, e, nullptr, nullptr, outp);
}

// Round 5
// 586.061 us; speedup vs baseline: 1.1002x; 1.1002x over previous
//
#include <hip/hip_runtime.h>

typedef __bf16 bf16x8 __attribute__((ext_vector_type(8)));
typedef __bf16 bf16x4 __attribute__((ext_vector_type(4)));
typedef float f32x4 __attribute__((ext_vector_type(4)));

__device__ __forceinline__ f32x4 mfma16(bf16x8 a, bf16x8 b, f32x4 c) {
  return __builtin_amdgcn_mfma_f32_16x16x32_bf16(a, b, c, 0, 0, 0);
}

__device__ __forceinline__ void load_lds16(const void* g, void* l) {
  __builtin_amdgcn_global_load_lds(
      (const __attribute__((address_space(1))) void*)g,
      (__attribute__((address_space(3))) void*)l, 16, 0, 0);
}

// Bijective XCD chunk swizzle (m204).
template <int NWG>
__device__ __forceinline__ int xcd_swz(int orig) {
  constexpr int NX = 8;
  constexpr int q = NWG / NX;
  constexpr int r = NWG % NX;
  const int xcd = orig % NX;
  const int pos = orig / NX;
  if constexpr (r == 0) {
    return xcd * q + pos;
  } else {
    return (xcd < r ? xcd * (q + 1) : r * (q + 1) + (xcd - r) * q) + pos;
  }
}

// ---------------- weight transpose + cast: W[k][n] (fp32) -> WT[n][k] (bf16) ----------------
__global__ __launch_bounds__(256) void prep_w_kernel(
    const float* __restrict__ Wq, const float* __restrict__ Wk,
    const float* __restrict__ Wv, const float* __restrict__ Wo,
    __bf16* __restrict__ WqT, __bf16* __restrict__ WkvT, __bf16* __restrict__ WoT) {
  __shared__ float tile[32][33];
  const int z = blockIdx.z;
  const float* W = (z == 0) ? Wq : (z == 1) ? Wk : (z == 2) ? Wv : Wo;
  __bf16* out = (z == 0) ? WqT : (z == 3) ? WoT : WkvT;
  const int rowOff = (z == 2) ? 768 : 0;
  const int tx = threadIdx.x, ty = threadIdx.y;
  const int x = blockIdx.x * 32 + tx;  // n (fast dim of W)
  const int y = blockIdx.y * 32 + ty;  // k
#pragma unroll
  for (int i = 0; i < 32; i += 8) tile[ty + i][tx] = W[(size_t)(y + i) * 768 + x];
  __syncthreads();
  const int nx = blockIdx.y * 32 + tx;  // k (fast dim of WT)
  const int ny = blockIdx.x * 32 + ty;  // n
#pragma unroll
  for (int i = 0; i < 32; i += 8)
    out[(size_t)(rowOff + ny + i) * 768 + nx] = (__bf16)tile[tx][ty + i];
}

// ---------------- LayerNorm + cast: e (fp32) -> en (bf16 normalized) ----------------
__global__ __launch_bounds__(256) void ln_kernel(
    const float* __restrict__ e, const float* __restrict__ gam,
    const float* __restrict__ bet, __bf16* __restrict__ en) {
  const int lane = threadIdx.x & 63;
  const int wid = threadIdx.x >> 6;
  const size_t row = (size_t)blockIdx.x * 4 + wid;
  const float* p = e + row * 768;
  float x[12];
  float sum = 0.f;
#pragma unroll
  for (int s = 0; s < 3; ++s) {
    f32x4 v = *(const f32x4*)(p + (s * 64 + lane) * 4);
#pragma unroll
    for (int q = 0; q < 4; ++q) { x[s * 4 + q] = v[q]; sum += v[q]; }
  }
#pragma unroll
  for (int d = 1; d < 64; d <<= 1) sum += __shfl_xor(sum, d);
  const float m = sum * (1.f / 768.f);
  float vs = 0.f;
#pragma unroll
  for (int q = 0; q < 12; ++q) { float d = x[q] - m; vs += d * d; }
#pragma unroll
  for (int d = 1; d < 64; d <<= 1) vs += __shfl_xor(vs, d);
  const float rr = rsqrtf(vs * (1.f / 768.f) + 1e-5f);
  __bf16* o = en + row * 768;
#pragma unroll
  for (int s = 0; s < 3; ++s) {
    f32x4 g4 = *(const f32x4*)(gam + (s * 64 + lane) * 4);
    f32x4 b4 = *(const f32x4*)(bet + (s * 64 + lane) * 4);
    bf16x4 pk;
#pragma unroll
    for (int q = 0; q < 4; ++q) pk[q] = (__bf16)((x[s * 4 + q] - m) * rr * g4[q] + b4[q]);
    *(bf16x4*)(o + (s * 64 + lane) * 4) = pk;
  }
}

// ---------------- fp32 -> bf16 cast (h) ----------------
__global__ __launch_bounds__(256) void cast_kernel(
    const float* __restrict__ in, __bf16* __restrict__ out, int n4) {
  int i = blockIdx.x * 256 + threadIdx.x;
  const int stride = gridDim.x * 256;
  for (; i < n4; i += stride) {
    f32x4 v = ((const f32x4*)in)[i];
    bf16x4 o;
#pragma unroll
    for (int q = 0; q < 4; ++q) o[q] = (__bf16)v[q];
    ((bf16x4*)out)[i] = o;
  }
}

// ---------------- 256x256 MFMA GEMM, 8 waves (2x4), single-buffer gload_lds ----------------
// A [M x 768] bf16 @ WT[n][k] bf16.  Each wave owns 128x64 out (64 MFMA/K-step).
enum { MODE_Q = 0, MODE_KV = 1, MODE_O = 2 };

template <int MODE, int NC, int NWG>
__global__ __launch_bounds__(512) void gemm_kernel(
    const __bf16* __restrict__ A,    // en (Q) / h_bf16 (KV) / o block-layout (O)
    const __bf16* __restrict__ WT,   // [N][768] bf16
    const float* __restrict__ bias0, const float* __restrict__ bias1,
    const float* __restrict__ eres,  // O only: fp32 residual e
    __bf16* __restrict__ dst0, __bf16* __restrict__ dst1,
    float* __restrict__ outp) {
  __shared__ __bf16 As[16384];  // [256][64]
  __shared__ __bf16 Bs[16384];  // [256][64]
  const int wgid = xcd_swz<NWG>(blockIdx.x);
  const int rowBase = (wgid / NC) * 256;
  const int colBase = (wgid % NC) * 256;
  const int t = threadIdx.x;
  const int lane = t & 63, wid = t >> 6;
  const int wm = wid >> 2, wn = wid & 3;       // 2x4 wave grid; wave tile 128x64
  const int lr = lane & 15, lg = lane >> 4;
  const int srow = t >> 3;                     // staging row 0..63 within pass
  const int skcol = (t & 7) * 8;               // staging k-offset
  f32x4 acc[8][4] = {};

  for (int kb = 0; kb < 12; ++kb) {
    // ---- stage A+B tiles (256x64 bf16 each), 4 passes x 16B/thread each ----
#pragma unroll
    for (int p = 0; p < 4; ++p) {
      const int row = p * 64 + srow;
      const __bf16* ga;
      if constexpr (MODE == MODE_O) {
        const int r = rowBase + row;
        ga = A + ((((size_t)(r >> 6)) * 12 + kb) << 12) + ((r & 63) << 6) + skcol;
      } else {
        ga = A + (size_t)(rowBase + row) * 768 + kb * 64 + skcol;
      }
      load_lds16(ga, &As[p * 4096 + t * 8]);
      const __bf16* gb = WT + (size_t)(colBase + row) * 768 + kb * 64 + skcol;
      load_lds16(gb, &Bs[p * 4096 + t * 8]);
    }
    __syncthreads();
    // ---- MFMA: 2 kc x 8 it x 4 jt = 64 per wave ----
#pragma unroll
    for (int kc = 0; kc < 2; ++kc) {
      bf16x8 a[8], b[4];
#pragma unroll
      for (int it = 0; it < 8; ++it)
        a[it] = *(const bf16x8*)&As[(wm * 128 + it * 16 + lr) * 64 + kc * 32 + lg * 8];
#pragma unroll
      for (int jt = 0; jt < 4; ++jt)
        b[jt] = *(const bf16x8*)&Bs[(wn * 64 + jt * 16 + lr) * 64 + kc * 32 + lg * 8];
#pragma unroll
      for (int it = 0; it < 8; ++it)
#pragma unroll
        for (int jt = 0; jt < 4; ++jt)
          acc[it][jt] = mfma16(a[it], b[jt], acc[it][jt]);
    }
    __syncthreads();
  }
  // ---- epilogue ----
  const int roww = rowBase + wm * 128;
  const int colw = colBase + wn * 64;
#pragma unroll
  for (int it = 0; it < 8; ++it) {
#pragma unroll
    for (int jt = 0; jt < 4; ++jt) {
      const int c = colw + jt * 16 + lr;
#pragma unroll
      for (int rg = 0; rg < 4; ++rg) {
        const int r = roww + it * 16 + lg * 4 + rg;
        const float val = acc[it][jt][rg];
        if constexpr (MODE == MODE_O) {
          outp[(size_t)r * 768 + c] = val + bias0[c] + eres[(size_t)r * 768 + c];
        } else if constexpr (MODE == MODE_Q) {
          dst0[((((size_t)(r >> 6)) * 12 + (c >> 6)) << 12) + ((r & 63) << 6) + (c & 63)] =
              (__bf16)(val + bias0[c]);
        } else {  // KV: c<768 -> k[bc][h][j][d]; else v transposed [bc][h][d][j]
          if (c < 768) {
            dst0[((((size_t)(r >> 6)) * 12 + (c >> 6)) << 12) + ((r & 63) << 6) + (c & 63)] =
                (__bf16)(val + bias0[c]);
          } else {
            const int c2 = c - 768;
            dst1[((((size_t)(r >> 6)) * 12 + (c2 >> 6)) << 12) + ((c2 & 63) << 6) + (r & 63)] =
                (__bf16)(val + bias1[c2]);
          }
        }
      }
    }
  }
}

// ---------------- attention: one wave per (b,c,n,h); i=j=d=64 ----------------
__global__ __launch_bounds__(64) void attn_kernel(
    const __bf16* __restrict__ q, const __bf16* __restrict__ k,
    const __bf16* __restrict__ v, __bf16* __restrict__ o) {
  const int gid = xcd_swz<12288>(blockIdx.x);
  const int n = gid & 3;
  const int bh = gid >> 2;
  const int h = bh % 12;
  const int bc = bh / 12;
  const __bf16* qp = q + (((size_t)(bc * 4 + n) * 12 + h) << 12);
  const __bf16* kp = k + (((size_t)bc * 12 + h) << 12);
  const __bf16* vp = v + (((size_t)bc * 12 + h) << 12);
  __bf16* op = o + (((size_t)(bc * 4 + n) * 12 + h) << 12);
  const int lane = threadIdx.x;
  const int lr = lane & 15, lg = lane >> 4;
  __shared__ __bf16 P[64][72];

  bf16x8 qf[4][2], kf[4][2];
#pragma unroll
  for (int it = 0; it < 4; ++it)
#pragma unroll
    for (int kc = 0; kc < 2; ++kc)
      qf[it][kc] = *(const bf16x8*)(qp + (it * 16 + lr) * 64 + kc * 32 + lg * 8);
#pragma unroll
  for (int jt = 0; jt < 4; ++jt)
#pragma unroll
    for (int kc = 0; kc < 2; ++kc)
      kf[jt][kc] = *(const bf16x8*)(kp + (jt * 16 + lr) * 64 + kc * 32 + lg * 8);

  // S^T = k @ q^T : lane holds S[i = it*16+lr][j = jt*16+lg*4+rg]
  f32x4 s[4][4] = {};
#pragma unroll
  for (int kc = 0; kc < 2; ++kc)
#pragma unroll
    for (int jt = 0; jt < 4; ++jt)
#pragma unroll
      for (int it = 0; it < 4; ++it)
        s[jt][it] = mfma16(kf[jt][kc], qf[it][kc], s[jt][it]);

  float recip[4];
#pragma unroll
  for (int it = 0; it < 4; ++it) {
    float m = -1e30f;
#pragma unroll
    for (int jt = 0; jt < 4; ++jt)
#pragma unroll
      for (int rg = 0; rg < 4; ++rg) m = fmaxf(m, s[jt][it][rg]);
    m = fmaxf(m, __shfl_xor(m, 16));
    m = fmaxf(m, __shfl_xor(m, 32));
    float sum = 0.f;
#pragma unroll
    for (int jt = 0; jt < 4; ++jt) {
      bf16x4 pk;
#pragma unroll
      for (int rg = 0; rg < 4; ++rg) {
        float p = __expf((s[jt][it][rg] - m) * 0.125f);
        sum += p;
        pk[rg] = (__bf16)p;
      }
      *(bf16x4*)&P[it * 16 + lr][jt * 16 + lg * 4] = pk;
    }
    sum += __shfl_xor(sum, 16);
    sum += __shfl_xor(sum, 32);
    recip[it] = 1.f / sum;
  }
  __syncthreads();

  bf16x8 vf[4][2];
#pragma unroll
  for (int dt = 0; dt < 4; ++dt)
#pragma unroll
    for (int kc = 0; kc < 2; ++kc)
      vf[dt][kc] = *(const bf16x8*)(vp + (dt * 16 + lr) * 64 + kc * 32 + lg * 8);
  f32x4 oacc[4][4] = {};
#pragma unroll
  for (int kc = 0; kc < 2; ++kc) {
    bf16x8 pf[4];
#pragma unroll
    for (int it = 0; it < 4; ++it)
      pf[it] = *(const bf16x8*)&P[it * 16 + lr][kc * 32 + lg * 8];
#pragma unroll
    for (int dt = 0; dt < 4; ++dt)
#pragma unroll
      for (int it = 0; it < 4; ++it)
        oacc[dt][it] = mfma16(vf[dt][kc], pf[it], oacc[dt][it]);
  }
#pragma unroll
  for (int it = 0; it < 4; ++it) {
    const float rc = recip[it];
#pragma unroll
    for (int dt = 0; dt < 4; ++dt) {
      bf16x4 pk;
#pragma unroll
      for (int rg = 0; rg < 4; ++rg) pk[rg] = (__bf16)(oacc[dt][it][rg] * rc);
      *(bf16x4*)(op + (size_t)(it * 16 + lr) * 64 + dt * 16 + lg * 4) = pk;
    }
  }
}

extern "C" void kernel_launch(void* const* d_in, const int* in_sizes, int n_in,
                              void* d_out, int out_size, void* d_ws, size_t ws_size,
                              hipStream_t stream) {
  const float* e  = (const float*)d_in[0];
  const float* h  = (const float*)d_in[1];
  const float* Wq = (const float*)d_in[2];
  const float* bq = (const float*)d_in[3];
  const float* Wk = (const float*)d_in[4];
  const float* bk = (const float*)d_in[5];
  const float* Wv = (const float*)d_in[6];
  const float* bv = (const float*)d_in[7];
  const float* Wo = (const float*)d_in[8];
  const float* bo = (const float*)d_in[9];
  const float* g  = (const float*)d_in[10];
  const float* b  = (const float*)d_in[11];
  float* outp = (float*)d_out;
  char* ws = (char*)d_ws;

  // workspace layout (aliasing: en dead after Q-GEMM, region reused by h/k/v)
  __bf16* WqT  = (__bf16*)(ws);                    // 1,179,648
  __bf16* WkvT = (__bf16*)(ws + 1179648);          // 2,359,296
  __bf16* WoT  = (__bf16*)(ws + 3538944);          // 1,179,648
  char* R1 = ws + 4718592;                         // 100,663,296 shared region
  __bf16* en    = (__bf16*)(R1);                   // 65536*768*2 (live: ln -> Q-GEMM)
  __bf16* h_bf  = (__bf16*)(R1);                   // 16384*768*2 (live after Q-GEMM)
  __bf16* k_ws  = (__bf16*)(R1 + 25165824);
  __bf16* v_ws  = (__bf16*)(R1 + 50331648);
  __bf16* q_ws  = (__bf16*)(ws + 105381888);       // 100,663,296 (o written in-place)

  prep_w_kernel<<<dim3(24, 24, 4), dim3(32, 8), 0, stream>>>(Wq, Wk, Wv, Wo, WqT, WkvT, WoT);
  ln_kernel<<<16384, 256, 0, stream>>>(e, g, b, en);
  gemm_kernel<MODE_Q, 3, 768><<<768, 512, 0, stream>>>(
      en, WqT, bq, nullptr, nullptr, q_ws, nullptr, nullptr);
  cast_kernel<<<2048, 256, 0, stream>>>(h, h_bf, 16384 * 768 / 4);
  gemm_kernel<MODE_KV, 6, 384><<<384, 512, 0, stream>>>(
      h_bf, WkvT, bk, bv, nullptr, k_ws, v_ws, nullptr);
  attn_kernel<<<12288, 64, 0, stream>>>(q_ws, k_ws, v_ws, q_ws);
  gemm_kernel<MODE_O, 3, 768><<<768, 512, 0, stream>>>(
      q_ws, WoT, bo, nullptr, e, nullptr, nullptr, outp);
}

// Round 6
// 508.744 us; speedup vs baseline: 1.2674x; 1.1520x over previous
//
#include <hip/hip_runtime.h>

typedef __bf16 bf16x8 __attribute__((ext_vector_type(8)));
typedef __bf16 bf16x4 __attribute__((ext_vector_type(4)));
typedef float f32x4 __attribute__((ext_vector_type(4)));

__device__ __forceinline__ f32x4 mfma16(bf16x8 a, bf16x8 b, f32x4 c) {
  return __builtin_amdgcn_mfma_f32_16x16x32_bf16(a, b, c, 0, 0, 0);
}

__device__ __forceinline__ void load_lds16(const void* g, void* l) {
  __builtin_amdgcn_global_load_lds(
      (const __attribute__((address_space(1))) void*)g,
      (__attribute__((address_space(3))) void*)l, 16, 0, 0);
}

// Bijective XCD chunk swizzle (m204).
template <int NWG>
__device__ __forceinline__ int xcd_swz(int orig) {
  constexpr int NX = 8;
  constexpr int q = NWG / NX;
  constexpr int r = NWG % NX;
  const int xcd = orig % NX;
  const int pos = orig / NX;
  if constexpr (r == 0) {
    return xcd * q + pos;
  } else {
    return (xcd < r ? xcd * (q + 1) : r * (q + 1) + (xcd - r) * q) + pos;
  }
}

// ---------------- weight transpose + cast: W[k][n] (fp32) -> WT[n][k] (bf16) ----------------
__global__ __launch_bounds__(256) void prep_w_kernel(
    const float* __restrict__ Wq, const float* __restrict__ Wk,
    const float* __restrict__ Wv, const float* __restrict__ Wo,
    __bf16* __restrict__ WqT, __bf16* __restrict__ WkvT, __bf16* __restrict__ WoT) {
  __shared__ float tile[32][33];
  const int z = blockIdx.z;
  const float* W = (z == 0) ? Wq : (z == 1) ? Wk : (z == 2) ? Wv : Wo;
  __bf16* out = (z == 0) ? WqT : (z == 3) ? WoT : WkvT;
  const int rowOff = (z == 2) ? 768 : 0;
  const int tx = threadIdx.x, ty = threadIdx.y;
  const int x = blockIdx.x * 32 + tx;  // n (fast dim of W)
  const int y = blockIdx.y * 32 + ty;  // k
#pragma unroll
  for (int i = 0; i < 32; i += 8) tile[ty + i][tx] = W[(size_t)(y + i) * 768 + x];
  __syncthreads();
  const int nx = blockIdx.y * 32 + tx;  // k (fast dim of WT)
  const int ny = blockIdx.x * 32 + ty;  // n
#pragma unroll
  for (int i = 0; i < 32; i += 8)
    out[(size_t)(rowOff + ny + i) * 768 + nx] = (__bf16)tile[tx][ty + i];
}

// ---------------- LayerNorm + cast: e (fp32) -> en (bf16 normalized) ----------------
__global__ __launch_bounds__(256) void ln_kernel(
    const float* __restrict__ e, const float* __restrict__ gam,
    const float* __restrict__ bet, __bf16* __restrict__ en) {
  const int lane = threadIdx.x & 63;
  const int wid = threadIdx.x >> 6;
  const size_t row = (size_t)blockIdx.x * 4 + wid;
  const float* p = e + row * 768;
  float x[12];
  float sum = 0.f;
#pragma unroll
  for (int s = 0; s < 3; ++s) {
    f32x4 v = *(const f32x4*)(p + (s * 64 + lane) * 4);
#pragma unroll
    for (int q = 0; q < 4; ++q) { x[s * 4 + q] = v[q]; sum += v[q]; }
  }
#pragma unroll
  for (int d = 1; d < 64; d <<= 1) sum += __shfl_xor(sum, d);
  const float m = sum * (1.f / 768.f);
  float vs = 0.f;
#pragma unroll
  for (int q = 0; q < 12; ++q) { float d = x[q] - m; vs += d * d; }
#pragma unroll
  for (int d = 1; d < 64; d <<= 1) vs += __shfl_xor(vs, d);
  const float rr = rsqrtf(vs * (1.f / 768.f) + 1e-5f);
  __bf16* o = en + row * 768;
#pragma unroll
  for (int s = 0; s < 3; ++s) {
    f32x4 g4 = *(const f32x4*)(gam + (s * 64 + lane) * 4);
    f32x4 b4 = *(const f32x4*)(bet + (s * 64 + lane) * 4);
    bf16x4 pk;
#pragma unroll
    for (int q = 0; q < 4; ++q) pk[q] = (__bf16)((x[s * 4 + q] - m) * rr * g4[q] + b4[q]);
    *(bf16x4*)(o + (s * 64 + lane) * 4) = pk;
  }
}

// ---------------- fp32 -> bf16 cast (h) ----------------
__global__ __launch_bounds__(256) void cast_kernel(
    const float* __restrict__ in, __bf16* __restrict__ out, int n4) {
  int i = blockIdx.x * 256 + threadIdx.x;
  const int stride = gridDim.x * 256;
  for (; i < n4; i += stride) {
    f32x4 v = ((const f32x4*)in)[i];
    bf16x4 o;
#pragma unroll
    for (int q = 0; q < 4; ++q) o[q] = (__bf16)v[q];
    ((bf16x4*)out)[i] = o;
  }
}

// ---------------- 128x128 MFMA GEMM, counted-vmcnt 2-buffer pipeline (T4) ----------------
// A [M x 768] bf16 @ WT[n][k] bf16.  4 waves (2x2), each 64x64 out.
// Never drain vmcnt in the loop: tile kb+1's loads stay in flight across
// compute(kb).  Every thread issues exactly 8 global_load_lds per stage
// (uniform), so per-wave vmcnt(8) + joint s_barrier == block-wide readiness.
enum { MODE_Q = 0, MODE_KV = 1, MODE_O = 2 };

template <int MODE, int NC, int NWG>
__global__ __launch_bounds__(256) void gemm_kernel(
    const __bf16* __restrict__ A,    // en (Q) / h_bf16 (KV) / o block-layout (O)
    const __bf16* __restrict__ WT,   // [N][768] bf16
    const float* __restrict__ bias0, const float* __restrict__ bias1,
    const float* __restrict__ eres,  // O only: fp32 residual e
    __bf16* __restrict__ dst0, __bf16* __restrict__ dst1,
    float* __restrict__ outp) {
  __shared__ __bf16 As[2][8192];  // [buf][128*64]
  __shared__ __bf16 Bs[2][8192];
  const int wgid = xcd_swz<NWG>(blockIdx.x);
  const int rowBase = (wgid / NC) * 128;
  const int colBase = (wgid % NC) * 128;
  const int t = threadIdx.x;
  const int lane = t & 63, wid = t >> 6;
  const int wm = wid >> 1, wn = wid & 1;
  const int lr = lane & 15, lg = lane >> 4;
  const int srow = lane >> 3;          // staging: row within 8-row chunk
  const int skcol = (lane & 7) * 8;    // staging: k-offset within 64-col tile
  f32x4 acc[4][4] = {};

  auto stage = [&](int kbb, int buf) {
#pragma unroll
    for (int s = 0; s < 4; ++s) {
      const int chunk = s * 4 + wid;          // 0..15, 8 rows each
      const int rowIn = chunk * 8 + srow;
      const __bf16* ga;
      if constexpr (MODE == MODE_O) {
        const int r = rowBase + rowIn;
        ga = A + ((((size_t)(r >> 6)) * 12 + kbb) << 12) + ((r & 63) << 6) + skcol;
      } else {
        ga = A + (size_t)(rowBase + rowIn) * 768 + kbb * 64 + skcol;
      }
      load_lds16(ga, &As[buf][chunk * 512]);
      const __bf16* gb = WT + (size_t)(colBase + rowIn) * 768 + kbb * 64 + skcol;
      load_lds16(gb, &Bs[buf][chunk * 512]);
    }
  };
  auto compute = [&](int buf) {
#pragma unroll
    for (int kc = 0; kc < 2; ++kc) {
      bf16x8 a[4], b[4];
#pragma unroll
      for (int it = 0; it < 4; ++it)
        a[it] = *(const bf16x8*)&As[buf][(wm * 64 + it * 16 + lr) * 64 + kc * 32 + lg * 8];
#pragma unroll
      for (int jt = 0; jt < 4; ++jt)
        b[jt] = *(const bf16x8*)&Bs[buf][(wn * 64 + jt * 16 + lr) * 64 + kc * 32 + lg * 8];
#pragma unroll
      for (int it = 0; it < 4; ++it)
#pragma unroll
        for (int jt = 0; jt < 4; ++jt)
          acc[it][jt] = mfma16(a[it], b[jt], acc[it][jt]);
    }
  };

  // prologue: two tiles in flight
  stage(0, 0);
  stage(1, 1);
#pragma unroll
  for (int kb = 0; kb < 12; ++kb) {
    if (kb < 11) {
      asm volatile("s_waitcnt vmcnt(8)" ::: "memory");  // tile kb landed; kb+1 flying
    } else {
      asm volatile("s_waitcnt vmcnt(0)" ::: "memory");  // final tile
    }
    __builtin_amdgcn_sched_barrier(0);
    __builtin_amdgcn_s_barrier();      // all waves' tile-kb loads complete
    compute(kb & 1);
    __builtin_amdgcn_s_barrier();      // all waves done reading buf kb&1
    if (kb < 10) stage(kb + 2, kb & 1);  // refill freed buffer; stays in flight
  }

  // ---- epilogue ----
  const int roww = rowBase + wm * 64;
  const int colw = colBase + wn * 64;
#pragma unroll
  for (int it = 0; it < 4; ++it) {
#pragma unroll
    for (int jt = 0; jt < 4; ++jt) {
      const int c = colw + jt * 16 + lr;
#pragma unroll
      for (int rg = 0; rg < 4; ++rg) {
        const int r = roww + it * 16 + lg * 4 + rg;
        const float val = acc[it][jt][rg];
        if constexpr (MODE == MODE_O) {
          outp[(size_t)r * 768 + c] = val + bias0[c] + eres[(size_t)r * 768 + c];
        } else if constexpr (MODE == MODE_Q) {
          dst0[((((size_t)(r >> 6)) * 12 + (c >> 6)) << 12) + ((r & 63) << 6) + (c & 63)] =
              (__bf16)(val + bias0[c]);
        } else {  // KV: c<768 -> k[bc][h][j][d]; else v transposed [bc][h][d][j]
          if (c < 768) {
            dst0[((((size_t)(r >> 6)) * 12 + (c >> 6)) << 12) + ((r & 63) << 6) + (c & 63)] =
                (__bf16)(val + bias0[c]);
          } else {
            const int c2 = c - 768;
            dst1[((((size_t)(r >> 6)) * 12 + (c2 >> 6)) << 12) + ((c2 & 63) << 6) + (r & 63)] =
                (__bf16)(val + bias1[c2]);
          }
        }
      }
    }
  }
}

// ---------------- attention: one wave per (b,c,n,h); i=j=d=64 ----------------
__global__ __launch_bounds__(64) void attn_kernel(
    const __bf16* __restrict__ q, const __bf16* __restrict__ k,
    const __bf16* __restrict__ v, __bf16* __restrict__ o) {
  const int gid = xcd_swz<12288>(blockIdx.x);
  const int n = gid & 3;
  const int bh = gid >> 2;
  const int h = bh % 12;
  const int bc = bh / 12;
  const __bf16* qp = q + (((size_t)(bc * 4 + n) * 12 + h) << 12);
  const __bf16* kp = k + (((size_t)bc * 12 + h) << 12);
  const __bf16* vp = v + (((size_t)bc * 12 + h) << 12);
  __bf16* op = o + (((size_t)(bc * 4 + n) * 12 + h) << 12);
  const int lane = threadIdx.x;
  const int lr = lane & 15, lg = lane >> 4;
  __shared__ __bf16 P[64][72];

  bf16x8 qf[4][2], kf[4][2];
#pragma unroll
  for (int it = 0; it < 4; ++it)
#pragma unroll
    for (int kc = 0; kc < 2; ++kc)
      qf[it][kc] = *(const bf16x8*)(qp + (it * 16 + lr) * 64 + kc * 32 + lg * 8);
#pragma unroll
  for (int jt = 0; jt < 4; ++jt)
#pragma unroll
    for (int kc = 0; kc < 2; ++kc)
      kf[jt][kc] = *(const bf16x8*)(kp + (jt * 16 + lr) * 64 + kc * 32 + lg * 8);

  // S^T = k @ q^T : lane holds S[i = it*16+lr][j = jt*16+lg*4+rg]
  f32x4 s[4][4] = {};
#pragma unroll
  for (int kc = 0; kc < 2; ++kc)
#pragma unroll
    for (int jt = 0; jt < 4; ++jt)
#pragma unroll
      for (int it = 0; it < 4; ++it)
        s[jt][it] = mfma16(kf[jt][kc], qf[it][kc], s[jt][it]);

  float recip[4];
#pragma unroll
  for (int it = 0; it < 4; ++it) {
    float m = -1e30f;
#pragma unroll
    for (int jt = 0; jt < 4; ++jt)
#pragma unroll
      for (int rg = 0; rg < 4; ++rg) m = fmaxf(m, s[jt][it][rg]);
    m = fmaxf(m, __shfl_xor(m, 16));
    m = fmaxf(m, __shfl_xor(m, 32));
    float sum = 0.f;
#pragma unroll
    for (int jt = 0; jt < 4; ++jt) {
      bf16x4 pk;
#pragma unroll
      for (int rg = 0; rg < 4; ++rg) {
        float p = __expf((s[jt][it][rg] - m) * 0.125f);
        sum += p;
        pk[rg] = (__bf16)p;
      }
      *(bf16x4*)&P[it * 16 + lr][jt * 16 + lg * 4] = pk;
    }
    sum += __shfl_xor(sum, 16);
    sum += __shfl_xor(sum, 32);
    recip[it] = 1.f / sum;
  }
  __syncthreads();

  bf16x8 vf[4][2];
#pragma unroll
  for (int dt = 0; dt < 4; ++dt)
#pragma unroll
    for (int kc = 0; kc < 2; ++kc)
      vf[dt][kc] = *(const bf16x8*)(vp + (dt * 16 + lr) * 64 + kc * 32 + lg * 8);
  f32x4 oacc[4][4] = {};
#pragma unroll
  for (int kc = 0; kc < 2; ++kc) {
    bf16x8 pf[4];
#pragma unroll
    for (int it = 0; it < 4; ++it)
      pf[it] = *(const bf16x8*)&P[it * 16 + lr][kc * 32 + lg * 8];
#pragma unroll
    for (int dt = 0; dt < 4; ++dt)
#pragma unroll
      for (int it = 0; it < 4; ++it)
        oacc[dt][it] = mfma16(vf[dt][kc], pf[it], oacc[dt][it]);
  }
#pragma unroll
  for (int it = 0; it < 4; ++it) {
    const float rc = recip[it];
#pragma unroll
    for (int dt = 0; dt < 4; ++dt) {
      bf16x4 pk;
#pragma unroll
      for (int rg = 0; rg < 4; ++rg) pk[rg] = (__bf16)(oacc[dt][it][rg] * rc);
      *(bf16x4*)(op + (size_t)(it * 16 + lr) * 64 + dt * 16 + lg * 4) = pk;
    }
  }
}

extern "C" void kernel_launch(void* const* d_in, const int* in_sizes, int n_in,
                              void* d_out, int out_size, void* d_ws, size_t ws_size,
                              hipStream_t stream) {
  const float* e  = (const float*)d_in[0];
  const float* h  = (const float*)d_in[1];
  const float* Wq = (const float*)d_in[2];
  const float* bq = (const float*)d_in[3];
  const float* Wk = (const float*)d_in[4];
  const float* bk = (const float*)d_in[5];
  const float* Wv = (const float*)d_in[6];
  const float* bv = (const float*)d_in[7];
  const float* Wo = (const float*)d_in[8];
  const float* bo = (const float*)d_in[9];
  const float* g  = (const float*)d_in[10];
  const float* b  = (const float*)d_in[11];
  float* outp = (float*)d_out;
  char* ws = (char*)d_ws;

  // workspace layout (aliasing: en dead after Q-GEMM, region reused by h/k/v)
  __bf16* WqT  = (__bf16*)(ws);                    // 1,179,648
  __bf16* WkvT = (__bf16*)(ws + 1179648);          // 2,359,296
  __bf16* WoT  = (__bf16*)(ws + 3538944);          // 1,179,648
  char* R1 = ws + 4718592;                         // 100,663,296 shared region
  __bf16* en    = (__bf16*)(R1);                   // 65536*768*2 (live: ln -> Q-GEMM)
  __bf16* h_bf  = (__bf16*)(R1);                   // 16384*768*2 (live after Q-GEMM)
  __bf16* k_ws  = (__bf16*)(R1 + 25165824);
  __bf16* v_ws  = (__bf16*)(R1 + 50331648);
  __bf16* q_ws  = (__bf16*)(ws + 105381888);       // 100,663,296 (o written in-place)

  prep_w_kernel<<<dim3(24, 24, 4), dim3(32, 8), 0, stream>>>(Wq, Wk, Wv, Wo, WqT, WkvT, WoT);
  ln_kernel<<<16384, 256, 0, stream>>>(e, g, b, en);
  gemm_kernel<MODE_Q, 6, 3072><<<3072, 256, 0, stream>>>(
      en, WqT, bq, nullptr, nullptr, q_ws, nullptr, nullptr);
  cast_kernel<<<2048, 256, 0, stream>>>(h, h_bf, 16384 * 768 / 4);
  gemm_kernel<MODE_KV, 12, 1536><<<1536, 256, 0, stream>>>(
      h_bf, WkvT, bk, bv, nullptr, k_ws, v_ws, nullptr);
  attn_kernel<<<12288, 64, 0, stream>>>(q_ws, k_ws, v_ws, q_ws);
  gemm_kernel<MODE_O, 6, 3072><<<3072, 256, 0, stream>>>(
      q_ws, WoT, bo, nullptr, e, nullptr, nullptr, outp);
}

// Round 7
// 488.567 us; speedup vs baseline: 1.3197x; 1.0413x over previous
//
#include <hip/hip_runtime.h>

typedef __bf16 bf16x8 __attribute__((ext_vector_type(8)));
typedef __bf16 bf16x4 __attribute__((ext_vector_type(4)));
typedef float f32x4 __attribute__((ext_vector_type(4)));

__device__ __forceinline__ f32x4 mfma16(bf16x8 a, bf16x8 b, f32x4 c) {
  return __builtin_amdgcn_mfma_f32_16x16x32_bf16(a, b, c, 0, 0, 0);
}

__device__ __forceinline__ void load_lds16(const void* g, void* l) {
  __builtin_amdgcn_global_load_lds(
      (const __attribute__((address_space(1))) void*)g,
      (__attribute__((address_space(3))) void*)l, 16, 0, 0);
}

// Bijective XCD chunk swizzle (m204).
template <int NWG>
__device__ __forceinline__ int xcd_swz(int orig) {
  constexpr int NX = 8;
  constexpr int q = NWG / NX;
  constexpr int r = NWG % NX;
  const int xcd = orig % NX;
  const int pos = orig / NX;
  if constexpr (r == 0) {
    return xcd * q + pos;
  } else {
    return (xcd < r ? xcd * (q + 1) : r * (q + 1) + (xcd - r) * q) + pos;
  }
}

// ---------------- weight transpose + cast: W[k][n] (fp32) -> WT[n][k] (bf16) ----------------
__global__ __launch_bounds__(256) void prep_w_kernel(
    const float* __restrict__ Wq, const float* __restrict__ Wk,
    const float* __restrict__ Wv, const float* __restrict__ Wo,
    __bf16* __restrict__ WqT, __bf16* __restrict__ WkvT, __bf16* __restrict__ WoT) {
  __shared__ float tile[32][33];
  const int z = blockIdx.z;
  const float* W = (z == 0) ? Wq : (z == 1) ? Wk : (z == 2) ? Wv : Wo;
  __bf16* out = (z == 0) ? WqT : (z == 3) ? WoT : WkvT;
  const int rowOff = (z == 2) ? 768 : 0;
  const int tx = threadIdx.x, ty = threadIdx.y;
  const int x = blockIdx.x * 32 + tx;  // n (fast dim of W)
  const int y = blockIdx.y * 32 + ty;  // k
#pragma unroll
  for (int i = 0; i < 32; i += 8) tile[ty + i][tx] = W[(size_t)(y + i) * 768 + x];
  __syncthreads();
  const int nx = blockIdx.y * 32 + tx;  // k (fast dim of WT)
  const int ny = blockIdx.x * 32 + ty;  // n
#pragma unroll
  for (int i = 0; i < 32; i += 8)
    out[(size_t)(rowOff + ny + i) * 768 + nx] = (__bf16)tile[tx][ty + i];
}

// ---------------- LayerNorm + cast: e (fp32) -> en (bf16 normalized) ----------------
__global__ __launch_bounds__(256) void ln_kernel(
    const float* __restrict__ e, const float* __restrict__ gam,
    const float* __restrict__ bet, __bf16* __restrict__ en) {
  const int lane = threadIdx.x & 63;
  const int wid = threadIdx.x >> 6;
  const size_t row = (size_t)blockIdx.x * 4 + wid;
  const float* p = e + row * 768;
  float x[12];
  float sum = 0.f;
#pragma unroll
  for (int s = 0; s < 3; ++s) {
    f32x4 v = *(const f32x4*)(p + (s * 64 + lane) * 4);
#pragma unroll
    for (int q = 0; q < 4; ++q) { x[s * 4 + q] = v[q]; sum += v[q]; }
  }
#pragma unroll
  for (int d = 1; d < 64; d <<= 1) sum += __shfl_xor(sum, d);
  const float m = sum * (1.f / 768.f);
  float vs = 0.f;
#pragma unroll
  for (int q = 0; q < 12; ++q) { float d = x[q] - m; vs += d * d; }
#pragma unroll
  for (int d = 1; d < 64; d <<= 1) vs += __shfl_xor(vs, d);
  const float rr = rsqrtf(vs * (1.f / 768.f) + 1e-5f);
  __bf16* o = en + row * 768;
#pragma unroll
  for (int s = 0; s < 3; ++s) {
    f32x4 g4 = *(const f32x4*)(gam + (s * 64 + lane) * 4);
    f32x4 b4 = *(const f32x4*)(bet + (s * 64 + lane) * 4);
    bf16x4 pk;
#pragma unroll
    for (int q = 0; q < 4; ++q) pk[q] = (__bf16)((x[s * 4 + q] - m) * rr * g4[q] + b4[q]);
    *(bf16x4*)(o + (s * 64 + lane) * 4) = pk;
  }
}

// ---------------- fp32 -> bf16 cast (h) ----------------
__global__ __launch_bounds__(256) void cast_kernel(
    const float* __restrict__ in, __bf16* __restrict__ out, int n4) {
  int i = blockIdx.x * 256 + threadIdx.x;
  const int stride = gridDim.x * 256;
  for (; i < n4; i += stride) {
    f32x4 v = ((const f32x4*)in)[i];
    bf16x4 o;
#pragma unroll
    for (int q = 0; q < 4; ++q) o[q] = (__bf16)v[q];
    ((bf16x4*)out)[i] = o;
  }
}

// ---------------- 128x128 MFMA GEMM, counted-vmcnt pipeline + T2 XOR swizzle ----------------
// LDS involution (per 128B row, 16B granules): col16' = col16 ^ (row&7).
// gload_lds writes LDS linearly, so the swizzle is applied by permuting the
// per-lane GLOBAL source column (inverse == same XOR) and XORing the ds_read
// column (rule #21: both sides, same involution).
enum { MODE_Q = 0, MODE_KV = 1, MODE_O = 2 };

template <int MODE, int NC, int NWG>
__global__ __launch_bounds__(256) void gemm_kernel(
    const __bf16* __restrict__ A,    // en (Q) / h_bf16 (KV) / o block-layout (O)
    const __bf16* __restrict__ WT,   // [N][768] bf16
    const float* __restrict__ bias0, const float* __restrict__ bias1,
    const float* __restrict__ eres,  // O only: fp32 residual e
    __bf16* __restrict__ dst0, __bf16* __restrict__ dst1,
    float* __restrict__ outp) {
  __shared__ __bf16 As[2][8192];  // [buf][128*64]
  __shared__ __bf16 Bs[2][8192];
  const int wgid = xcd_swz<NWG>(blockIdx.x);
  const int rowBase = (wgid / NC) * 128;
  const int colBase = (wgid % NC) * 128;
  const int t = threadIdx.x;
  const int lane = t & 63, wid = t >> 6;
  const int wm = wid >> 1, wn = wid & 1;
  const int lr = lane & 15, lg = lane >> 4;
  const int srow = lane >> 3;                          // staging row within 8-row chunk
  const int skcol = ((lane & 7) ^ srow) * 8;           // XOR-swizzled source column
  f32x4 acc[4][4] = {};

  auto stage = [&](int kbb, int buf) {
#pragma unroll
    for (int s = 0; s < 4; ++s) {
      const int chunk = s * 4 + wid;          // 0..15, 8 rows each
      const int rowIn = chunk * 8 + srow;
      const __bf16* ga;
      if constexpr (MODE == MODE_O) {
        const int r = rowBase + rowIn;
        ga = A + ((((size_t)(r >> 6)) * 12 + kbb) << 12) + ((r & 63) << 6) + skcol;
      } else {
        ga = A + (size_t)(rowBase + rowIn) * 768 + kbb * 64 + skcol;
      }
      load_lds16(ga, &As[buf][chunk * 512]);
      const __bf16* gb = WT + (size_t)(colBase + rowIn) * 768 + kbb * 64 + skcol;
      load_lds16(gb, &Bs[buf][chunk * 512]);
    }
  };
  auto compute = [&](int buf) {
#pragma unroll
    for (int kc = 0; kc < 2; ++kc) {
      bf16x8 a[4], b[4];
      const int c8 = (kc * 4 + lg) ^ (lr & 7);   // swizzled 8-elem column group
#pragma unroll
      for (int it = 0; it < 4; ++it)
        a[it] = *(const bf16x8*)&As[buf][(wm * 64 + it * 16 + lr) * 64 + c8 * 8];
#pragma unroll
      for (int jt = 0; jt < 4; ++jt)
        b[jt] = *(const bf16x8*)&Bs[buf][(wn * 64 + jt * 16 + lr) * 64 + c8 * 8];
#pragma unroll
      for (int it = 0; it < 4; ++it)
#pragma unroll
        for (int jt = 0; jt < 4; ++jt)
          acc[it][jt] = mfma16(a[it], b[jt], acc[it][jt]);
    }
  };

  // prologue: two tiles in flight
  stage(0, 0);
  stage(1, 1);
#pragma unroll
  for (int kb = 0; kb < 12; ++kb) {
    if (kb < 11) {
      asm volatile("s_waitcnt vmcnt(8)" ::: "memory");  // tile kb landed; kb+1 flying
    } else {
      asm volatile("s_waitcnt vmcnt(0)" ::: "memory");  // final tile
    }
    __builtin_amdgcn_sched_barrier(0);
    __builtin_amdgcn_s_barrier();      // all waves' tile-kb loads complete
    compute(kb & 1);
    __builtin_amdgcn_s_barrier();      // all waves done reading buf kb&1
    if (kb < 10) stage(kb + 2, kb & 1);  // refill freed buffer; stays in flight
  }

  // ---- epilogue ----
  const int roww = rowBase + wm * 64;
  const int colw = colBase + wn * 64;
#pragma unroll
  for (int it = 0; it < 4; ++it) {
#pragma unroll
    for (int jt = 0; jt < 4; ++jt) {
      const int c = colw + jt * 16 + lr;
#pragma unroll
      for (int rg = 0; rg < 4; ++rg) {
        const int r = roww + it * 16 + lg * 4 + rg;
        const float val = acc[it][jt][rg];
        if constexpr (MODE == MODE_O) {
          outp[(size_t)r * 768 + c] = val + bias0[c] + eres[(size_t)r * 768 + c];
        } else if constexpr (MODE == MODE_Q) {
          dst0[((((size_t)(r >> 6)) * 12 + (c >> 6)) << 12) + ((r & 63) << 6) + (c & 63)] =
              (__bf16)(val + bias0[c]);
        } else {  // KV: c<768 -> k[bc][h][j][d]; else v transposed [bc][h][d][j]
          if (c < 768) {
            dst0[((((size_t)(r >> 6)) * 12 + (c >> 6)) << 12) + ((r & 63) << 6) + (c & 63)] =
                (__bf16)(val + bias0[c]);
          } else {
            const int c2 = c - 768;
            dst1[((((size_t)(r >> 6)) * 12 + (c2 >> 6)) << 12) + ((c2 & 63) << 6) + (r & 63)] =
                (__bf16)(val + bias1[c2]);
          }
        }
      }
    }
  }
}

// ---------------- attention: one wave per (b,c,n,h); i=j=d=64 ----------------
__global__ __launch_bounds__(64) void attn_kernel(
    const __bf16* __restrict__ q, const __bf16* __restrict__ k,
    const __bf16* __restrict__ v, __bf16* __restrict__ o) {
  const int gid = xcd_swz<12288>(blockIdx.x);
  const int n = gid & 3;
  const int bh = gid >> 2;
  const int h = bh % 12;
  const int bc = bh / 12;
  const __bf16* qp = q + (((size_t)(bc * 4 + n) * 12 + h) << 12);
  const __bf16* kp = k + (((size_t)bc * 12 + h) << 12);
  const __bf16* vp = v + (((size_t)bc * 12 + h) << 12);
  __bf16* op = o + (((size_t)(bc * 4 + n) * 12 + h) << 12);
  const int lane = threadIdx.x;
  const int lr = lane & 15, lg = lane >> 4;
  __shared__ __bf16 P[64][72];

  bf16x8 qf[4][2], kf[4][2];
#pragma unroll
  for (int it = 0; it < 4; ++it)
#pragma unroll
    for (int kc = 0; kc < 2; ++kc)
      qf[it][kc] = *(const bf16x8*)(qp + (it * 16 + lr) * 64 + kc * 32 + lg * 8);
#pragma unroll
  for (int jt = 0; jt < 4; ++jt)
#pragma unroll
    for (int kc = 0; kc < 2; ++kc)
      kf[jt][kc] = *(const bf16x8*)(kp + (jt * 16 + lr) * 64 + kc * 32 + lg * 8);

  // S^T = k @ q^T : lane holds S[i = it*16+lr][j = jt*16+lg*4+rg]
  f32x4 s[4][4] = {};
#pragma unroll
  for (int kc = 0; kc < 2; ++kc)
#pragma unroll
    for (int jt = 0; jt < 4; ++jt)
#pragma unroll
      for (int it = 0; it < 4; ++it)
        s[jt][it] = mfma16(kf[jt][kc], qf[it][kc], s[jt][it]);

  float recip[4];
#pragma unroll
  for (int it = 0; it < 4; ++it) {
    float m = -1e30f;
#pragma unroll
    for (int jt = 0; jt < 4; ++jt)
#pragma unroll
      for (int rg = 0; rg < 4; ++rg) m = fmaxf(m, s[jt][it][rg]);
    m = fmaxf(m, __shfl_xor(m, 16));
    m = fmaxf(m, __shfl_xor(m, 32));
    float sum = 0.f;
#pragma unroll
    for (int jt = 0; jt < 4; ++jt) {
      bf16x4 pk;
#pragma unroll
      for (int rg = 0; rg < 4; ++rg) {
        float p = __expf((s[jt][it][rg] - m) * 0.125f);
        sum += p;
        pk[rg] = (__bf16)p;
      }
      *(bf16x4*)&P[it * 16 + lr][jt * 16 + lg * 4] = pk;
    }
    sum += __shfl_xor(sum, 16);
    sum += __shfl_xor(sum, 32);
    recip[it] = 1.f / sum;
  }
  __syncthreads();

  bf16x8 vf[4][2];
#pragma unroll
  for (int dt = 0; dt < 4; ++dt)
#pragma unroll
    for (int kc = 0; kc < 2; ++kc)
      vf[dt][kc] = *(const bf16x8*)(vp + (dt * 16 + lr) * 64 + kc * 32 + lg * 8);
  f32x4 oacc[4][4] = {};
#pragma unroll
  for (int kc = 0; kc < 2; ++kc) {
    bf16x8 pf[4];
#pragma unroll
    for (int it = 0; it < 4; ++it)
      pf[it] = *(const bf16x8*)&P[it * 16 + lr][kc * 32 + lg * 8];
#pragma unroll
    for (int dt = 0; dt < 4; ++dt)
#pragma unroll
      for (int it = 0; it < 4; ++it)
        oacc[dt][it] = mfma16(vf[dt][kc], pf[it], oacc[dt][it]);
  }
#pragma unroll
  for (int it = 0; it < 4; ++it) {
    const float rc = recip[it];
#pragma unroll
    for (int dt = 0; dt < 4; ++dt) {
      bf16x4 pk;
#pragma unroll
      for (int rg = 0; rg < 4; ++rg) pk[rg] = (__bf16)(oacc[dt][it][rg] * rc);
      *(bf16x4*)(op + (size_t)(it * 16 + lr) * 64 + dt * 16 + lg * 4) = pk;
    }
  }
}

extern "C" void kernel_launch(void* const* d_in, const int* in_sizes, int n_in,
                              void* d_out, int out_size, void* d_ws, size_t ws_size,
                              hipStream_t stream) {
  const float* e  = (const float*)d_in[0];
  const float* h  = (const float*)d_in[1];
  const float* Wq = (const float*)d_in[2];
  const float* bq = (const float*)d_in[3];
  const float* Wk = (const float*)d_in[4];
  const float* bk = (const float*)d_in[5];
  const float* Wv = (const float*)d_in[6];
  const float* bv = (const float*)d_in[7];
  const float* Wo = (const float*)d_in[8];
  const float* bo = (const float*)d_in[9];
  const float* g  = (const float*)d_in[10];
  const float* b  = (const float*)d_in[11];
  float* outp = (float*)d_out;
  char* ws = (char*)d_ws;

  // workspace layout (aliasing: en dead after Q-GEMM, region reused by h/k/v)
  __bf16* WqT  = (__bf16*)(ws);                    // 1,179,648
  __bf16* WkvT = (__bf16*)(ws + 1179648);          // 2,359,296
  __bf16* WoT  = (__bf16*)(ws + 3538944);          // 1,179,648
  char* R1 = ws + 4718592;                         // 100,663,296 shared region
  __bf16* en    = (__bf16*)(R1);                   // 65536*768*2 (live: ln -> Q-GEMM)
  __bf16* h_bf  = (__bf16*)(R1);                   // 16384*768*2 (live after Q-GEMM)
  __bf16* k_ws  = (__bf16*)(R1 + 25165824);
  __bf16* v_ws  = (__bf16*)(R1 + 50331648);
  __bf16* q_ws  = (__bf16*)(ws + 105381888);       // 100,663,296 (o written in-place)

  prep_w_kernel<<<dim3(24, 24, 4), dim3(32, 8), 0, stream>>>(Wq, Wk, Wv, Wo, WqT, WkvT, WoT);
  ln_kernel<<<16384, 256, 0, stream>>>(e, g, b, en);
  gemm_kernel<MODE_Q, 6, 3072><<<3072, 256, 0, stream>>>(
      en, WqT, bq, nullptr, nullptr, q_ws, nullptr, nullptr);
  cast_kernel<<<2048, 256, 0, stream>>>(h, h_bf, 16384 * 768 / 4);
  gemm_kernel<MODE_KV, 12, 1536><<<1536, 256, 0, stream>>>(
      h_bf, WkvT, bk, bv, nullptr, k_ws, v_ws, nullptr);
  attn_kernel<<<12288, 64, 0, stream>>>(q_ws, k_ws, v_ws, q_ws);
  gemm_kernel<MODE_O, 6, 3072><<<3072, 256, 0, stream>>>(
      q_ws, WoT, bo, nullptr, e, nullptr, nullptr, outp);
}